// Round 6
// baseline (1561.866 us; speedup 1.0000x reference)
//
#include <hip/hip_runtime.h>
#include <math.h>

#define N_NODES 100000
#define N_EDGES 3200000
#define N_GRAPHS 64
#define BW 128                               // nodes per bucket
#define LSH 7
#define LMASK 127u
#define NBUCK ((N_NODES + BW - 1) / BW)      // 782
#define CHUNK_E 16384
#define NCHUNK ((N_EDGES + CHUNK_E - 1) / CHUNK_E)  // 196
#define HSTRIDE 68                           // 64 + pad: 16B-aligned rows, 2-way banks only

// ---- pass A: per-chunk bucket histogram (LDS only) ----
__global__ void k_count(const int* __restrict__ dst, unsigned int* __restrict__ counts,
                        unsigned int* __restrict__ totals) {
    __shared__ unsigned int h[NBUCK];
    for (int i = threadIdx.x; i < NBUCK; i += blockDim.x) h[i] = 0u;
    __syncthreads();
    int e0 = blockIdx.x * CHUNK_E;
    int e1 = min(e0 + CHUNK_E, N_EDGES);
    for (int e = e0 + threadIdx.x; e < e1; e += blockDim.x)
        atomicAdd(&h[dst[e] >> LSH], 1u);
    __syncthreads();
    for (int i = threadIdx.x; i < NBUCK; i += blockDim.x) {
        counts[(size_t)blockIdx.x * NBUCK + i] = h[i];
        if (h[i]) atomicAdd(&totals[i], h[i]);
    }
}

// ---- pass B: exclusive scan of bucket totals -> base ----
__global__ void k_scanb(const unsigned int* __restrict__ totals, unsigned int* __restrict__ base) {
    __shared__ unsigned int sd[1024];
    int t = threadIdx.x;
    unsigned int v = (t < NBUCK) ? totals[t] : 0u;
    sd[t] = v;
    __syncthreads();
    for (int o = 1; o < 1024; o <<= 1) {
        unsigned int tv = (t >= o) ? sd[t - o] : 0u;
        __syncthreads();
        sd[t] += tv;
        __syncthreads();
    }
    if (t < NBUCK) base[t] = sd[t] - v;
    if (t == 0) base[NBUCK] = N_EDGES;
}

// ---- pass C: per-bucket scan over chunks -> counts becomes start[chunk][bucket] ----
__global__ void k_scanc(unsigned int* __restrict__ counts, const unsigned int* __restrict__ base) {
    __shared__ unsigned int sd[256];
    int bk = blockIdx.x;
    int t = threadIdx.x;
    unsigned int v = (t < NCHUNK) ? counts[(size_t)t * NBUCK + bk] : 0u;
    sd[t] = v;
    __syncthreads();
    for (int o = 1; o < 256; o <<= 1) {
        unsigned int tv = (t >= o) ? sd[t - o] : 0u;
        __syncthreads();
        sd[t] += tv;
        __syncthreads();
    }
    if (t < NCHUNK) counts[(size_t)t * NBUCK + bk] = base[bk] + sd[t] - v;
}

// ---- pass D: place edges — zero global atomics ----
__global__ void k_part(const int* __restrict__ src, const int* __restrict__ dst,
                       const unsigned int* __restrict__ counts, unsigned int* __restrict__ packed) {
    __shared__ unsigned int sstart[NBUCK];
    __shared__ unsigned int lcur[NBUCK];
    for (int i = threadIdx.x; i < NBUCK; i += blockDim.x) {
        sstart[i] = counts[(size_t)blockIdx.x * NBUCK + i];
        lcur[i] = 0u;
    }
    __syncthreads();
    int e0 = blockIdx.x * CHUNK_E;
    int e1 = min(e0 + CHUNK_E, N_EDGES);
    for (int e = e0 + threadIdx.x; e < e1; e += blockDim.x) {
        int d = dst[e];
        int bk = d >> LSH;
        unsigned int pos = sstart[bk] + atomicAdd(&lcur[bk], 1u);
        packed[pos] = ((unsigned int)src[e] << LSH) | ((unsigned int)d & LMASK);
    }
}

// ---- per-bucket degree -> dinv, s ----
__global__ void k_deg(const unsigned int* __restrict__ base, const unsigned int* __restrict__ packed,
                      const float* __restrict__ x, float* __restrict__ dinv, float* __restrict__ s) {
    __shared__ unsigned int cnt[BW];
    if (threadIdx.x < BW) cnt[threadIdx.x] = 0u;
    __syncthreads();
    int b = blockIdx.x;
    unsigned int e0 = base[b], e1 = base[b + 1];
    for (unsigned int e = e0 + threadIdx.x; e < e1; e += blockDim.x)
        atomicAdd(&cnt[packed[e] & LMASK], 1u);
    __syncthreads();
    int n = b * BW + threadIdx.x;
    if (threadIdx.x < BW && n < N_NODES) {
        float di = 1.0f / sqrtf((float)(cnt[threadIdx.x] + 1u));  // +1 self-loop
        dinv[n] = di;
        s[n] = x[n] * di;
    }
}

// ---- graph node counts via binary search (no atomics) ----
__global__ void k_gcnt(const int* __restrict__ batch, float* __restrict__ gcnt) {
    __shared__ int lb[N_GRAPHS + 1];
    int b = threadIdx.x;
    if (b <= N_GRAPHS) {
        int lo = 0, hi = N_NODES;
        while (lo < hi) {
            int mid = (lo + hi) >> 1;
            if (batch[mid] < b) lo = mid + 1; else hi = mid;
        }
        lb[b] = lo;
    }
    __syncthreads();
    if (b < N_GRAPHS) gcnt[b] = (float)(lb[b + 1] - lb[b]);
}

// ---- layer 1: LDS scalar agg -> ac[n] = (a=dinv, c=dinv^2*(agg1+s)) ----
__global__ void k_l1(const unsigned int* __restrict__ base, const unsigned int* __restrict__ packed,
                     const float* __restrict__ dinv, const float* __restrict__ s,
                     float2* __restrict__ ac) {
    __shared__ float acc[BW];
    if (threadIdx.x < BW) acc[threadIdx.x] = 0.0f;
    __syncthreads();
    int b = blockIdx.x;
    unsigned int e0 = base[b], e1 = base[b + 1];
    for (unsigned int e = e0 + threadIdx.x; e < e1; e += blockDim.x) {
        unsigned int p = packed[e];
        atomicAdd(&acc[p & LMASK], s[p >> LSH]);
    }
    __syncthreads();
    int t = threadIdx.x;
    int n = b * BW + t;
    if (t < BW && n < N_NODES) {
        float di = dinv[n];
        float sum = acc[t] + s[n];        // agg1 + self
        ac[n] = make_float2(di, di * di * sum);   // (dinv, dinv * t)
    }
}

// ---- layer 2: scalar gather + 64-dim LDS H accumulation + matvec + relu + pooling ----
__global__ void k_l2(const unsigned int* __restrict__ base, const unsigned int* __restrict__ packed,
                     const float2* __restrict__ ac,
                     const float* __restrict__ W1, const float* __restrict__ b1,
                     const float* __restrict__ W2, const float* __restrict__ b2,
                     const int* __restrict__ batch, float* __restrict__ gsum) {
    __shared__ float Hs[BW * HSTRIDE];   // 34.8 KB
    int g = threadIdx.x >> 5;            // 8 groups of 32 lanes
    int k = threadIdx.x & 31;

    // zero H
    for (int i = threadIdx.x; i < BW * HSTRIDE; i += blockDim.x) Hs[i] = 0.0f;

    // per-lane constants
    float w1a = W1[k], w1b = W1[k + 32];
    float b1a = b1[k], b1b = b1[k + 32];
    float b2k = b2[k];
    float w2c[64];
#pragma unroll
    for (int j = 0; j < 64; j++) w2c[j] = W2[j * 32 + k];   // column k of W2, coalesced
    __syncthreads();

    int b = blockIdx.x;
    unsigned int e0 = base[b], e1 = base[b + 1];

    unsigned int e = e0 + (unsigned int)g * 4u;
    for (; e + 4 <= e1; e += 32) {
        unsigned int p0 = packed[e + 0], p1 = packed[e + 1], p2 = packed[e + 2], p3 = packed[e + 3];
        float2 q0 = ac[p0 >> LSH];
        float2 q1 = ac[p1 >> LSH];
        float2 q2 = ac[p2 >> LSH];
        float2 q3 = ac[p3 >> LSH];
        int d0 = (int)(p0 & LMASK) * HSTRIDE, d1 = (int)(p1 & LMASK) * HSTRIDE;
        int d2 = (int)(p2 & LMASK) * HSTRIDE, d3 = (int)(p3 & LMASK) * HSTRIDE;
        atomicAdd(&Hs[d0 + k],      fmaxf(q0.y * w1a + q0.x * b1a, 0.0f));
        atomicAdd(&Hs[d0 + k + 32], fmaxf(q0.y * w1b + q0.x * b1b, 0.0f));
        atomicAdd(&Hs[d1 + k],      fmaxf(q1.y * w1a + q1.x * b1a, 0.0f));
        atomicAdd(&Hs[d1 + k + 32], fmaxf(q1.y * w1b + q1.x * b1b, 0.0f));
        atomicAdd(&Hs[d2 + k],      fmaxf(q2.y * w1a + q2.x * b1a, 0.0f));
        atomicAdd(&Hs[d2 + k + 32], fmaxf(q2.y * w1b + q2.x * b1b, 0.0f));
        atomicAdd(&Hs[d3 + k],      fmaxf(q3.y * w1a + q3.x * b1a, 0.0f));
        atomicAdd(&Hs[d3 + k + 32], fmaxf(q3.y * w1b + q3.x * b1b, 0.0f));
    }
    // tail (each group's last partial window)
    {
        unsigned int te = (e1 < e + 4) ? e1 : (e + 4);
        for (unsigned int j = e; j < te; j++) {
            unsigned int p = packed[j];
            float2 qq = ac[p >> LSH];
            int dd = (int)(p & LMASK) * HSTRIDE;
            atomicAdd(&Hs[dd + k],      fmaxf(qq.y * w1a + qq.x * b1a, 0.0f));
            atomicAdd(&Hs[dd + k + 32], fmaxf(qq.y * w1b + qq.x * b1b, 0.0f));
        }
    }
    __syncthreads();

    // epilogue: self-loop + matvec + relu + run-accumulated pooling (batch sorted)
    float racc = 0.0f;
    int curg = -1;
    for (int i = g; i < BW; i += 8) {
        int n = b * BW + i;
        if (n >= N_NODES) break;
        float2 acd = ac[n];                       // broadcast
        float* Hrow = &Hs[i * HSTRIDE];
        // self-loop contribution (same group owns this row now; wave-order makes it visible)
        Hrow[k]      += fmaxf(acd.y * w1a + acd.x * b1a, 0.0f);
        Hrow[k + 32] += fmaxf(acd.y * w1b + acd.x * b1b, 0.0f);
        // out_k = relu(dinv * (H row . W2[:,k]) + b2[k])
        float accv = 0.0f;
#pragma unroll
        for (int jj = 0; jj < 16; jj++) {
            float4 hv = *(float4*)&Hrow[4 * jj];
            accv += hv.x * w2c[4 * jj + 0] + hv.y * w2c[4 * jj + 1]
                  + hv.z * w2c[4 * jj + 2] + hv.w * w2c[4 * jj + 3];
        }
        float v = fmaxf(acd.x * accv + b2k, 0.0f);
        int gb = batch[n];
        if (gb != curg) {
            if (curg >= 0) atomicAdd(&gsum[curg * 32 + k], racc);
            racc = 0.0f; curg = gb;
        }
        racc += v;
    }
    if (curg >= 0) atomicAdd(&gsum[curg * 32 + k], racc);
}

// ---- readout ----
__global__ void k_readout(const float* __restrict__ gsum, const float* __restrict__ gcnt,
                          const float* __restrict__ Wfc, const float* __restrict__ bfc,
                          float* __restrict__ out) {
    int b = threadIdx.x;
    if (b < N_GRAPHS) {
        float inv = 1.0f / fmaxf(gcnt[b], 1.0f);
        float acc = bfc[0];
#pragma unroll
        for (int k = 0; k < 32; k++) acc += gsum[b * 32 + k] * inv * Wfc[k];
        out[b] = 1.0f / (1.0f + expf(-acc));
    }
}

// ---- launch ----
extern "C" void kernel_launch(void* const* d_in, const int* in_sizes, int n_in,
                              void* d_out, int out_size, void* d_ws, size_t ws_size,
                              hipStream_t stream) {
    const float* x    = (const float*)d_in[0];
    const int*   ei   = (const int*)d_in[1];
    const int*   batch= (const int*)d_in[2];
    const float* W1   = (const float*)d_in[3];
    const float* b1   = (const float*)d_in[4];
    const float* W2   = (const float*)d_in[5];
    const float* b2   = (const float*)d_in[6];
    const float* Wfc  = (const float*)d_in[7];
    const float* bfc  = (const float*)d_in[8];
    float* out = (float*)d_out;

    const int* srcIdx = ei;
    const int* dstIdx = ei + N_EDGES;

    char* w = (char*)d_ws;
    unsigned int* counts = (unsigned int*)w; w += ((size_t)NCHUNK * NBUCK + 64) * 4;
    unsigned int* totals = (unsigned int*)w; w += ((NBUCK + 64) & ~63) * 4;
    unsigned int* base   = (unsigned int*)w; w += ((NBUCK + 1 + 63) & ~63) * 4;
    unsigned int* packed = (unsigned int*)w; w += (size_t)N_EDGES * 4;
    float* dinv = (float*)w;                 w += (size_t)N_NODES * 4;
    float* sbuf = (float*)w;                 w += (size_t)N_NODES * 4;
    float2* ac  = (float2*)w;                w += (size_t)N_NODES * 8;
    float* gsum = (float*)w;                 w += (size_t)N_GRAPHS * 32 * 4;
    float* gcnt = (float*)w;                 w += (size_t)N_GRAPHS * 4;

    hipMemsetAsync(totals, 0, (size_t)NBUCK * 4, stream);
    hipMemsetAsync(gsum, 0, (size_t)N_GRAPHS * 32 * 4, stream);

    const int B = 256;
    k_count<<<NCHUNK, B, 0, stream>>>(dstIdx, counts, totals);
    k_scanb<<<1, 1024, 0, stream>>>(totals, base);
    k_scanc<<<NBUCK, 256, 0, stream>>>(counts, base);
    k_part <<<NCHUNK, B, 0, stream>>>(srcIdx, dstIdx, counts, packed);
    k_gcnt <<<1, 128, 0, stream>>>(batch, gcnt);
    k_deg  <<<NBUCK, B, 0, stream>>>(base, packed, x, dinv, sbuf);
    k_l1   <<<NBUCK, B, 0, stream>>>(base, packed, dinv, sbuf, ac);
    k_l2   <<<NBUCK, B, 0, stream>>>(base, packed, ac, W1, b1, W2, b2, batch, gsum);
    k_readout<<<1, 64, 0, stream>>>(gsum, gcnt, Wfc, bfc, out);
}

// Round 7
// 360.518 us; speedup vs baseline: 4.3323x; 4.3323x over previous
//
#include <hip/hip_runtime.h>
#include <math.h>

#define N_NODES 100000
#define N_EDGES 3200000
#define N_GRAPHS 64
#define BW 128                               // nodes per bucket
#define LSH 7
#define LMASK 127u
#define NBUCK ((N_NODES + BW - 1) / BW)      // 782
#define CHUNK_E 16384
#define NCHUNK ((N_EDGES + CHUNK_E - 1) / CHUNK_E)  // 196
#define POOL_SCALE 1024.0f
#define POOL_INV (1.0f / 1024.0f)

// ---- pass A: per-chunk bucket histogram (int LDS atomics — native) ----
__global__ void k_count(const int* __restrict__ dst, unsigned int* __restrict__ counts,
                        unsigned int* __restrict__ totals) {
    __shared__ unsigned int h[NBUCK];
    for (int i = threadIdx.x; i < NBUCK; i += blockDim.x) h[i] = 0u;
    __syncthreads();
    int e0 = blockIdx.x * CHUNK_E;
    int e1 = min(e0 + CHUNK_E, N_EDGES);
    for (int e = e0 + threadIdx.x; e < e1; e += blockDim.x)
        atomicAdd(&h[dst[e] >> LSH], 1u);
    __syncthreads();
    for (int i = threadIdx.x; i < NBUCK; i += blockDim.x) {
        counts[(size_t)blockIdx.x * NBUCK + i] = h[i];
        if (h[i]) atomicAdd(&totals[i], h[i]);
    }
}

// ---- pass B: exclusive scan of bucket totals -> base ----
__global__ void k_scanb(const unsigned int* __restrict__ totals, unsigned int* __restrict__ base) {
    __shared__ unsigned int sd[1024];
    int t = threadIdx.x;
    unsigned int v = (t < NBUCK) ? totals[t] : 0u;
    sd[t] = v;
    __syncthreads();
    for (int o = 1; o < 1024; o <<= 1) {
        unsigned int tv = (t >= o) ? sd[t - o] : 0u;
        __syncthreads();
        sd[t] += tv;
        __syncthreads();
    }
    if (t < NBUCK) base[t] = sd[t] - v;
    if (t == 0) base[NBUCK] = N_EDGES;
}

// ---- pass C: per-bucket scan over chunks -> counts = start[chunk][bucket] ----
__global__ void k_scanc(unsigned int* __restrict__ counts, const unsigned int* __restrict__ base) {
    __shared__ unsigned int sd[256];
    int bk = blockIdx.x;
    int t = threadIdx.x;
    unsigned int v = (t < NCHUNK) ? counts[(size_t)t * NBUCK + bk] : 0u;
    sd[t] = v;
    __syncthreads();
    for (int o = 1; o < 256; o <<= 1) {
        unsigned int tv = (t >= o) ? sd[t - o] : 0u;
        __syncthreads();
        sd[t] += tv;
        __syncthreads();
    }
    if (t < NCHUNK) counts[(size_t)t * NBUCK + bk] = base[bk] + sd[t] - v;
}

// ---- pass D: place edges into buckets (int LDS cursors — native) ----
__global__ void k_part(const int* __restrict__ src, const int* __restrict__ dst,
                       const unsigned int* __restrict__ counts, unsigned int* __restrict__ packed) {
    __shared__ unsigned int sstart[NBUCK];
    __shared__ unsigned int lcur[NBUCK];
    for (int i = threadIdx.x; i < NBUCK; i += blockDim.x) {
        sstart[i] = counts[(size_t)blockIdx.x * NBUCK + i];
        lcur[i] = 0u;
    }
    __syncthreads();
    int e0 = blockIdx.x * CHUNK_E;
    int e1 = min(e0 + CHUNK_E, N_EDGES);
    for (int e = e0 + threadIdx.x; e < e1; e += blockDim.x) {
        int d = dst[e];
        int bk = d >> LSH;
        unsigned int pos = sstart[bk] + atomicAdd(&lcur[bk], 1u);
        packed[pos] = ((unsigned int)src[e] << LSH) | ((unsigned int)d & LMASK);
    }
}

// ---- pass E: per-bucket exact dst sort -> packed2 + rowstart (all int) ----
__global__ void k_sort(const unsigned int* __restrict__ base, const unsigned int* __restrict__ packed,
                       unsigned int* __restrict__ packed2, unsigned int* __restrict__ rowstart) {
    __shared__ unsigned int hist[BW];
    __shared__ unsigned int scan[BW];
    __shared__ unsigned int cur[BW];
    int b = blockIdx.x;
    unsigned int e0 = base[b], e1 = base[b + 1];
    if (threadIdx.x < BW) hist[threadIdx.x] = 0u;
    __syncthreads();
    for (unsigned int e = e0 + threadIdx.x; e < e1; e += blockDim.x)
        atomicAdd(&hist[packed[e] & LMASK], 1u);
    __syncthreads();
    if (threadIdx.x < BW) scan[threadIdx.x] = hist[threadIdx.x];
    __syncthreads();
    for (int o = 1; o < BW; o <<= 1) {
        unsigned int v = 0u;
        if (threadIdx.x < BW && threadIdx.x >= (unsigned)o) v = scan[threadIdx.x - o];
        __syncthreads();
        if (threadIdx.x < BW && threadIdx.x >= (unsigned)o) scan[threadIdx.x] += v;
        __syncthreads();
    }
    if (threadIdx.x < BW) {
        unsigned int excl = scan[threadIdx.x] - hist[threadIdx.x];
        cur[threadIdx.x] = excl;
        rowstart[b * BW + threadIdx.x] = e0 + excl;
    }
    __syncthreads();
    for (unsigned int e = e0 + threadIdx.x; e < e1; e += blockDim.x) {
        unsigned int p = packed[e];
        unsigned int pos = e0 + atomicAdd(&cur[p & LMASK], 1u);
        packed2[pos] = p;
    }
}

// ---- dinv/s from rowstart diffs (no atomics) ----
__global__ void k_dinv(const unsigned int* __restrict__ rowstart, const float* __restrict__ x,
                       float* __restrict__ dinv, float* __restrict__ s) {
    int n = blockIdx.x * blockDim.x + threadIdx.x;
    if (n < N_NODES) {
        unsigned int deg = rowstart[n + 1] - rowstart[n];
        float di = 1.0f / sqrtf((float)(deg + 1u));  // +1 self-loop
        dinv[n] = di;
        s[n] = x[n] * di;
    }
}

// ---- graph node counts via binary search (no atomics) ----
__global__ void k_gcnt(const int* __restrict__ batch, float* __restrict__ gcnt) {
    __shared__ int lb[N_GRAPHS + 1];
    int b = threadIdx.x;
    if (b <= N_GRAPHS) {
        int lo = 0, hi = N_NODES;
        while (lo < hi) {
            int mid = (lo + hi) >> 1;
            if (batch[mid] < b) lo = mid + 1; else hi = mid;
        }
        lb[b] = lo;
    }
    __syncthreads();
    if (b < N_GRAPHS) gcnt[b] = (float)(lb[b + 1] - lb[b]);
}

// ---- layer 1: lane-per-edge gather + shfl reduce -> ac (no atomics) ----
__global__ void k_l1(const unsigned int* __restrict__ rowstart, const unsigned int* __restrict__ packed2,
                     const float* __restrict__ dinv, const float* __restrict__ s,
                     float2* __restrict__ ac) {
    int g = threadIdx.x >> 5, k = threadIdx.x & 31;
    int b = blockIdx.x;
    for (int d = g; d < BW; d += 8) {
        int n = b * BW + d;
        if (n >= N_NODES) break;
        unsigned int rs = rowstart[n], re = rowstart[n + 1];
        float sum = 0.0f;
        for (unsigned int e = rs + k; e < re; e += 32)
            sum += s[packed2[e] >> LSH];
        sum += __shfl_xor(sum, 1);
        sum += __shfl_xor(sum, 2);
        sum += __shfl_xor(sum, 4);
        sum += __shfl_xor(sum, 8);
        sum += __shfl_xor(sum, 16);   // masks <32: stays within the 32-lane half
        if (k == 0) {
            float di = dinv[n];
            ac[n] = make_float2(di, di * di * (sum + s[n]));
        }
    }
}

// ---- layer 2: per-node register H accumulation + LDS matvec + int-atomic pooling ----
__global__ __launch_bounds__(256, 2)
void k_l2(const unsigned int* __restrict__ rowstart, const unsigned int* __restrict__ packed2,
          const float2* __restrict__ ac,
          const float* __restrict__ W1, const float* __restrict__ b1,
          const float* __restrict__ W2, const float* __restrict__ b2,
          const int* __restrict__ batch, int* __restrict__ gsumi) {
    __shared__ float W2s[64 * 32];
    __shared__ float Hrow[8][72];   // 288B rows: 16B-aligned; write pattern 2 lanes/bank (free)
    int g = threadIdx.x >> 5, k = threadIdx.x & 31;
    for (int i = threadIdx.x; i < 64 * 32; i += blockDim.x) W2s[i] = W2[i];
    float w1a = W1[k], w1b = W1[k + 32];
    float b1a = b1[k], b1b = b1[k + 32];
    float b2k = b2[k];
    __syncthreads();
    // W2 column k into registers (loop-invariant across nodes)
    float w2c[64];
#pragma unroll
    for (int j = 0; j < 64; j++) w2c[j] = W2s[j * 32 + k];

    int b = blockIdx.x;
    float racc = 0.0f;
    int curg = -1;
    for (int d = g; d < BW; d += 8) {
        int n = b * BW + d;
        if (n >= N_NODES) break;
        unsigned int rs = rowstart[n], re = rowstart[n + 1];
        float2 acn = ac[n];
        // self-loop contribution
        float h0 = fmaxf(acn.y * w1a + acn.x * b1a, 0.0f);
        float h1 = fmaxf(acn.y * w1b + acn.x * b1b, 0.0f);
        unsigned int e = rs;
        for (; e + 4 <= re; e += 4) {
            unsigned int p0 = packed2[e], p1 = packed2[e + 1], p2 = packed2[e + 2], p3 = packed2[e + 3];
            float2 a0 = ac[p0 >> LSH];
            float2 a1 = ac[p1 >> LSH];
            float2 a2 = ac[p2 >> LSH];
            float2 a3 = ac[p3 >> LSH];
            h0 += fmaxf(a0.y * w1a + a0.x * b1a, 0.0f);
            h1 += fmaxf(a0.y * w1b + a0.x * b1b, 0.0f);
            h0 += fmaxf(a1.y * w1a + a1.x * b1a, 0.0f);
            h1 += fmaxf(a1.y * w1b + a1.x * b1b, 0.0f);
            h0 += fmaxf(a2.y * w1a + a2.x * b1a, 0.0f);
            h1 += fmaxf(a2.y * w1b + a2.x * b1b, 0.0f);
            h0 += fmaxf(a3.y * w1a + a3.x * b1a, 0.0f);
            h1 += fmaxf(a3.y * w1b + a3.x * b1b, 0.0f);
        }
        for (; e < re; e++) {
            unsigned int p = packed2[e];
            float2 aa = ac[p >> LSH];
            h0 += fmaxf(aa.y * w1a + aa.x * b1a, 0.0f);
            h1 += fmaxf(aa.y * w1b + aa.x * b1b, 0.0f);
        }
        // matvec: out_k = relu(dinv_n * (H . W2[:,k]) + b2[k]) via LDS round-trip
        Hrow[g][k] = h0;
        Hrow[g][k + 32] = h1;   // same-wave ds ordering makes these visible to the half's reads
        float accv = 0.0f;
#pragma unroll
        for (int jj = 0; jj < 16; jj++) {
            float4 hv = *(const float4*)&Hrow[g][4 * jj];
            accv += hv.x * w2c[4 * jj + 0] + hv.y * w2c[4 * jj + 1]
                  + hv.z * w2c[4 * jj + 2] + hv.w * w2c[4 * jj + 3];
        }
        float v = fmaxf(acn.x * accv + b2k, 0.0f);
        int gb = batch[n];
        if (gb != curg) {
            if (curg >= 0) atomicAdd(&gsumi[curg * 32 + k], __float2int_rn(racc * POOL_SCALE));
            racc = 0.0f; curg = gb;
        }
        racc += v;
    }
    if (curg >= 0) atomicAdd(&gsumi[curg * 32 + k], __float2int_rn(racc * POOL_SCALE));
}

// ---- readout ----
__global__ void k_readout(const int* __restrict__ gsumi, const float* __restrict__ gcnt,
                          const float* __restrict__ Wfc, const float* __restrict__ bfc,
                          float* __restrict__ out) {
    int b = threadIdx.x;
    if (b < N_GRAPHS) {
        float inv = 1.0f / fmaxf(gcnt[b], 1.0f);
        float acc = bfc[0];
#pragma unroll
        for (int k = 0; k < 32; k++)
            acc += (float)gsumi[b * 32 + k] * POOL_INV * inv * Wfc[k];
        out[b] = 1.0f / (1.0f + expf(-acc));
    }
}

// ---- launch ----
extern "C" void kernel_launch(void* const* d_in, const int* in_sizes, int n_in,
                              void* d_out, int out_size, void* d_ws, size_t ws_size,
                              hipStream_t stream) {
    const float* x    = (const float*)d_in[0];
    const int*   ei   = (const int*)d_in[1];
    const int*   batch= (const int*)d_in[2];
    const float* W1   = (const float*)d_in[3];
    const float* b1   = (const float*)d_in[4];
    const float* W2   = (const float*)d_in[5];
    const float* b2   = (const float*)d_in[6];
    const float* Wfc  = (const float*)d_in[7];
    const float* bfc  = (const float*)d_in[8];
    float* out = (float*)d_out;

    const int* srcIdx = ei;
    const int* dstIdx = ei + N_EDGES;

    char* w = (char*)d_ws;
    unsigned int* counts  = (unsigned int*)w; w += ((size_t)NCHUNK * NBUCK + 64) * 4;
    unsigned int* totals  = (unsigned int*)w; w += ((NBUCK + 64) & ~63) * 4;
    unsigned int* base    = (unsigned int*)w; w += ((NBUCK + 1 + 63) & ~63) * 4;
    unsigned int* packed  = (unsigned int*)w; w += (size_t)N_EDGES * 4;
    unsigned int* packed2 = (unsigned int*)w; w += (size_t)N_EDGES * 4;
    unsigned int* rowstart= (unsigned int*)w; w += (size_t)(NBUCK * BW + 64) * 4;
    float* dinv = (float*)w;                  w += (size_t)N_NODES * 4;
    float* sbuf = (float*)w;                  w += (size_t)N_NODES * 4;
    float2* ac  = (float2*)w;                 w += (size_t)N_NODES * 8;
    int* gsumi  = (int*)w;                    w += (size_t)N_GRAPHS * 32 * 4;
    float* gcnt = (float*)w;                  w += (size_t)N_GRAPHS * 4;

    hipMemsetAsync(totals, 0, (size_t)NBUCK * 4, stream);
    hipMemsetAsync(gsumi, 0, (size_t)N_GRAPHS * 32 * 4, stream);

    const int B = 256;
    k_count<<<NCHUNK, B, 0, stream>>>(dstIdx, counts, totals);
    k_scanb<<<1, 1024, 0, stream>>>(totals, base);
    k_scanc<<<NBUCK, 256, 0, stream>>>(counts, base);
    k_part <<<NCHUNK, B, 0, stream>>>(srcIdx, dstIdx, counts, packed);
    k_sort <<<NBUCK, B, 0, stream>>>(base, packed, packed2, rowstart);
    k_dinv <<<(N_NODES + B - 1) / B, B, 0, stream>>>(rowstart, x, dinv, sbuf);
    k_gcnt <<<1, 128, 0, stream>>>(batch, gcnt);
    k_l1   <<<NBUCK, B, 0, stream>>>(rowstart, packed2, dinv, sbuf, ac);
    k_l2   <<<NBUCK, B, 0, stream>>>(rowstart, packed2, ac, W1, b1, W2, b2, batch, gsumi);
    k_readout<<<1, 64, 0, stream>>>(gsumi, gcnt, Wfc, bfc, out);
}